// Round 1
// baseline (184.220 us; speedup 1.0000x reference)
//
#include <hip/hip_runtime.h>
#include <hip/hip_bf16.h>

// Problem constants: B=8, L=1024, D=1024, H=16, K=64
// Reference (bug reproduced): out = ((X@Win+bin -> Q,K,V) ; (Q Kt /8) V ; @Wout + bout)
// No softmax => linear attention => Q @ (Kt V / 8)  (64x64 per (b,h)).

typedef __attribute__((ext_vector_type(8))) short short8;
typedef __attribute__((ext_vector_type(4))) float f32x4;

static __device__ __forceinline__ short f2bf(float f) {
  __hip_bfloat16 h = __float2bfloat16(f);
  return __builtin_bit_cast(short, h);
}
static __device__ __forceinline__ float bf2f(short s) {
  unsigned int u = ((unsigned int)(unsigned short)s) << 16;
  return __builtin_bit_cast(float, u);
}

// ---------------- cast fp32 -> bf16 (vectorized, exact-size grid) --------
__global__ __launch_bounds__(256) void cast_f32_bf16_kernel(
    const float* __restrict__ in, __hip_bfloat16* __restrict__ out) {
  size_t i = ((size_t)blockIdx.x * 256 + threadIdx.x) * 8;
  float4 v0 = *(const float4*)(in + i);
  float4 v1 = *(const float4*)(in + i + 4);
  short8 o;
  o[0] = f2bf(v0.x); o[1] = f2bf(v0.y); o[2] = f2bf(v0.z); o[3] = f2bf(v0.w);
  o[4] = f2bf(v1.x); o[5] = f2bf(v1.y); o[6] = f2bf(v1.z); o[7] = f2bf(v1.w);
  *(short8*)((__hip_bfloat16*)out + i) = o;
}

// ---------------- transpose + cast fp32 (R x C) -> bf16 (C x R) ----------
__global__ __launch_bounds__(256) void transpose_cast_kernel(
    const float* __restrict__ in, __hip_bfloat16* __restrict__ out, int R, int C) {
  __shared__ float tile[32][33];
  int c0 = blockIdx.x * 32, r0 = blockIdx.y * 32;
  int tx = threadIdx.x & 31;
  int ty = threadIdx.x >> 5;  // 0..7
#pragma unroll
  for (int i = 0; i < 4; ++i)
    tile[ty + i * 8][tx] = in[(size_t)(r0 + ty + i * 8) * C + c0 + tx];
  __syncthreads();
#pragma unroll
  for (int i = 0; i < 4; ++i)
    out[(size_t)(c0 + ty + i * 8) * R + r0 + tx] =
        __float2bfloat16(tile[tx][ty + i * 8]);
}

// ---------------- bf16 MFMA GEMM: C(MxN) = A(MxKd) @ Bt(NxKd)^T + bias ----
// A row-major bf16, Bt row-major bf16 (i.e. original B pre-transposed).
// 128x128 tile, 4 waves (2x2), each wave 64x64 = 4x4 frags of 16x16x32.
static __device__ __forceinline__ void store_out(__hip_bfloat16* p, float v) {
  *p = __float2bfloat16(v);
}
static __device__ __forceinline__ void store_out(float* p, float v) { *p = v; }

template <typename OutT>
__global__ __launch_bounds__(256) void gemm_bt_kernel(
    const __hip_bfloat16* __restrict__ A, const __hip_bfloat16* __restrict__ Bt,
    const float* __restrict__ bias, OutT* __restrict__ C,
    int M, int N, int Kd) {
  __shared__ __align__(16) __hip_bfloat16 As[128][40];  // +8 pad: ~conflict-free b128
  __shared__ __align__(16) __hip_bfloat16 Bs[128][40];

  const int t = threadIdx.x;
  const int bn = blockIdx.x, bm = blockIdx.y;
  const int m0 = bm * 128, n0 = bn * 128;
  const int w = t >> 6, lane = t & 63;
  const int wr = w >> 1, wc = w & 1;          // wave -> 64x64 quadrant
  const int lr = lane & 15, kg = lane >> 4;   // frag row/col, k-group

  f32x4 acc[4][4] = {};

  const int steps = Kd >> 5;  // BK = 32
  for (int kt = 0; kt < steps; ++kt) {
    const int kcolb = kt * 32;
#pragma unroll
    for (int rep = 0; rep < 2; ++rep) {
      int g = t + rep * 256;          // 0..511 granules of 8 bf16
      int row = g >> 2, kgp = g & 3;  // row 0..127
      int kcol = kcolb + kgp * 8;
      *(short8*)&As[row][kgp * 8] =
          *(const short8*)(A + (size_t)(m0 + row) * Kd + kcol);
      *(short8*)&Bs[row][kgp * 8] =
          *(const short8*)(Bt + (size_t)(n0 + row) * Kd + kcol);
    }
    __syncthreads();

    short8 af[4], bfv[4];
#pragma unroll
    for (int mi = 0; mi < 4; ++mi)
      af[mi] = *(const short8*)&As[wr * 64 + mi * 16 + lr][kg * 8];
#pragma unroll
    for (int ni = 0; ni < 4; ++ni)
      bfv[ni] = *(const short8*)&Bs[wc * 64 + ni * 16 + lr][kg * 8];
#pragma unroll
    for (int mi = 0; mi < 4; ++mi)
#pragma unroll
      for (int ni = 0; ni < 4; ++ni)
        acc[mi][ni] = __builtin_amdgcn_mfma_f32_16x16x32_bf16(
            af[mi], bfv[ni], acc[mi][ni], 0, 0, 0);
    __syncthreads();
  }

  // C/D layout (m89-verified): col = lane&15, row = (lane>>4)*4 + reg
#pragma unroll
  for (int mi = 0; mi < 4; ++mi) {
    int row0 = m0 + wr * 64 + mi * 16 + kg * 4;
#pragma unroll
    for (int ni = 0; ni < 4; ++ni) {
      int col = n0 + wc * 64 + ni * 16 + lr;
      float bv = bias[col];
#pragma unroll
      for (int r = 0; r < 4; ++r)
        store_out(&C[(size_t)(row0 + r) * N + col], acc[mi][ni][r] + bv);
    }
  }
}

// ---------------- S[b,h] = (K_h^T @ V_h) / 8   (64x64 per (b,h)) ----------
__global__ __launch_bounds__(256) void ktv_kernel(
    const __hip_bfloat16* __restrict__ qkv, float* __restrict__ S) {
  __shared__ __align__(16) float Ks[64][68];
  __shared__ __align__(16) float Vs[64][68];
  const int bh = blockIdx.x;                 // 0..127
  const int b = bh >> 4, h = bh & 15;
  const __hip_bfloat16* base = qkv + (size_t)b * 1024 * 3072;
  const int hoff = h * 64;
  const int t = threadIdx.x;
  const int i0 = (t >> 4) * 4;   // output row block
  const int j0 = (t & 15) * 4;   // output col block
  const int srow = t >> 2;       // staging row 0..63
  const int sg0 = t & 3;         // staging granule base

  f32x4 acc[4] = {};             // acc[ii] = S[i0+ii][j0..j0+3]

  for (int c = 0; c < 16; ++c) {
    int l0 = c * 64;
#pragma unroll
    for (int rep = 0; rep < 2; ++rep) {
      int g = sg0 + rep * 4;  // 0..7 granules of 8
      const __hip_bfloat16* rowp = base + (size_t)(l0 + srow) * 3072;
      short8 kv = *(const short8*)(rowp + 1024 + hoff + g * 8);
      short8 vv = *(const short8*)(rowp + 2048 + hoff + g * 8);
      f32x4 k0, k1, v0, v1;
#pragma unroll
      for (int e = 0; e < 4; ++e) {
        k0[e] = bf2f(kv[e]); k1[e] = bf2f(kv[4 + e]);
        v0[e] = bf2f(vv[e]); v1[e] = bf2f(vv[4 + e]);
      }
      *(f32x4*)&Ks[srow][g * 8] = k0;
      *(f32x4*)&Ks[srow][g * 8 + 4] = k1;
      *(f32x4*)&Vs[srow][g * 8] = v0;
      *(f32x4*)&Vs[srow][g * 8 + 4] = v1;
    }
    __syncthreads();
#pragma unroll 8
    for (int l = 0; l < 64; ++l) {
      f32x4 kq = *(const f32x4*)&Ks[l][i0];
      f32x4 vq = *(const f32x4*)&Vs[l][j0];
#pragma unroll
      for (int ii = 0; ii < 4; ++ii) acc[ii] += kq[ii] * vq;
    }
    __syncthreads();
  }

  float* Sp = S + (size_t)bh * 4096;
#pragma unroll
  for (int ii = 0; ii < 4; ++ii)
#pragma unroll
    for (int jj = 0; jj < 4; ++jj)
      Sp[(i0 + ii) * 64 + j0 + jj] = acc[ii][jj] * 0.125f;
}

// ---------------- attn = Q_h @ S[b,h]  -> bf16 (B*L x D, head-interleaved) -
__global__ __launch_bounds__(256) void qs_kernel(
    const __hip_bfloat16* __restrict__ qkv, const float* __restrict__ S,
    __hip_bfloat16* __restrict__ attn) {
  __shared__ __align__(16) float Ql[128][68];
  __shared__ __align__(16) float Sl[64][68];
  const int bh = blockIdx.x;   // 0..127
  const int rblk = blockIdx.y; // 0..7
  const int b = bh >> 4, h = bh & 15;
  const __hip_bfloat16* Qp = qkv + (size_t)b * 1024 * 3072 + h * 64;
  const int r0 = rblk * 128;
  const int t = threadIdx.x;

  // stage Q chunk (128 x 64) as f32
#pragma unroll
  for (int rep = 0; rep < 4; ++rep) {
    int g = t + rep * 256;       // 0..1023 granules of 8
    int row = g >> 3, gg = g & 7;
    short8 qv = *(const short8*)(Qp + (size_t)(r0 + row) * 3072 + gg * 8);
    f32x4 f0, f1;
#pragma unroll
    for (int e = 0; e < 4; ++e) { f0[e] = bf2f(qv[e]); f1[e] = bf2f(qv[4 + e]); }
    *(f32x4*)&Ql[row][gg * 8] = f0;
    *(f32x4*)&Ql[row][gg * 8 + 4] = f1;
  }
  // stage S (64 x 64 f32)
  const float* Sp = S + (size_t)bh * 4096;
#pragma unroll
  for (int rep = 0; rep < 4; ++rep) {
    int g = t + rep * 256;        // 0..1023 float4 granules
    int row = g >> 4, gg = g & 15;
    *(f32x4*)&Sl[row][gg * 4] = *(const f32x4*)&Sp[row * 64 + gg * 4];
  }
  __syncthreads();

  const int rt0 = (t >> 3) * 4;   // 4 rows
  const int j0 = (t & 7) * 8;     // 8 cols
  f32x4 accA[4] = {}, accB[4] = {};
#pragma unroll 4
  for (int i = 0; i < 64; i += 4) {
    f32x4 q[4], s0[4], s1[4];
#pragma unroll
    for (int rr = 0; rr < 4; ++rr) q[rr] = *(const f32x4*)&Ql[rt0 + rr][i];
#pragma unroll
    for (int ii = 0; ii < 4; ++ii) {
      s0[ii] = *(const f32x4*)&Sl[i + ii][j0];
      s1[ii] = *(const f32x4*)&Sl[i + ii][j0 + 4];
    }
#pragma unroll
    for (int ii = 0; ii < 4; ++ii)
#pragma unroll
      for (int rr = 0; rr < 4; ++rr) {
        accA[rr] += q[rr][ii] * s0[ii];
        accB[rr] += q[rr][ii] * s1[ii];
      }
  }

#pragma unroll
  for (int rr = 0; rr < 4; ++rr) {
    short8 o;
#pragma unroll
    for (int e = 0; e < 4; ++e) {
      o[e] = f2bf(accA[rr][e]);
      o[4 + e] = f2bf(accB[rr][e]);
    }
    *(short8*)(attn + (size_t)(b * 1024 + r0 + rt0 + rr) * 1024 + h * 64 + j0) = o;
  }
}

extern "C" void kernel_launch(void* const* d_in, const int* in_sizes, int n_in,
                              void* d_out, int out_size, void* d_ws, size_t ws_size,
                              hipStream_t stream) {
  const float* x = (const float*)d_in[0];
  const float* w_in = (const float*)d_in[1];
  const float* b_in = (const float*)d_in[2];
  const float* w_out = (const float*)d_in[3];
  const float* b_out = (const float*)d_in[4];
  float* out = (float*)d_out;

  char* ws = (char*)d_ws;
  __hip_bfloat16* x_bf = (__hip_bfloat16*)ws;   ws += (size_t)8192 * 1024 * 2;
  __hip_bfloat16* w_inT = (__hip_bfloat16*)ws;  ws += (size_t)3072 * 1024 * 2;
  __hip_bfloat16* w_outT = (__hip_bfloat16*)ws; ws += (size_t)1024 * 1024 * 2;
  __hip_bfloat16* qkv = (__hip_bfloat16*)ws;    ws += (size_t)8192 * 3072 * 2;
  float* Sbuf = (float*)ws;                     ws += (size_t)128 * 64 * 64 * 4;
  __hip_bfloat16* attn = (__hip_bfloat16*)ws;   ws += (size_t)8192 * 1024 * 2;

  // casts / transposes
  cast_f32_bf16_kernel<<<4096, 256, 0, stream>>>(x, x_bf);              // 8192x1024
  transpose_cast_kernel<<<dim3(96, 32), 256, 0, stream>>>(w_in, w_inT, 1024, 3072);
  transpose_cast_kernel<<<dim3(32, 32), 256, 0, stream>>>(w_out, w_outT, 1024, 1024);

  // GEMM1: qkv = x @ w_in + b_in   (8192 x 3072, Kd=1024) -> bf16
  gemm_bt_kernel<__hip_bfloat16><<<dim3(24, 64), 256, 0, stream>>>(
      x_bf, w_inT, b_in, qkv, 8192, 3072, 1024);

  // S = Kt V / 8 per (b,h)
  ktv_kernel<<<128, 256, 0, stream>>>(qkv, Sbuf);

  // attn = Q @ S per (b,h)
  qs_kernel<<<dim3(128, 8), 256, 0, stream>>>(qkv, Sbuf, attn);

  // GEMM4: out = attn @ w_out + b_out  (8192 x 1024, Kd=1024) -> fp32
  gemm_bt_kernel<float><<<dim3(8, 64), 256, 0, stream>>>(
      attn, w_outT, b_out, out, 8192, 1024, 1024);
}

// Round 2
// 162.023 us; speedup vs baseline: 1.1370x; 1.1370x over previous
//
#include <hip/hip_runtime.h>
#include <hip/hip_bf16.h>

// Problem constants: B=8, L=1024, D=1024, H=16, K=64
// Reference (bug reproduced): no softmax => linear attention:
//   out = ( Q @ (K^T V / 8) ) @ Wout + bout, per (b,h) 64x64 inner matrix.

typedef __attribute__((ext_vector_type(8))) short short8;
typedef __attribute__((ext_vector_type(4))) float f32x4;

static __device__ __forceinline__ short f2bf(float f) {
  __hip_bfloat16 h = __float2bfloat16(f);
  return __builtin_bit_cast(short, h);
}
static __device__ __forceinline__ float bf2f(short s) {
  unsigned int u = ((unsigned int)(unsigned short)s) << 16;
  return __builtin_bit_cast(float, u);
}

// async global->LDS, 16B per lane, wave-uniform LDS base (HW adds lane*16)
static __device__ __forceinline__ void gload_lds16(const void* g, void* l) {
  __builtin_amdgcn_global_load_lds(
      (const __attribute__((address_space(1))) void*)g,
      (__attribute__((address_space(3))) void*)l, 16, 0, 0);
}

// ---------------- cast fp32 -> bf16 (vectorized, exact-size grid) --------
__global__ __launch_bounds__(256) void cast_f32_bf16_kernel(
    const float* __restrict__ in, __hip_bfloat16* __restrict__ out) {
  size_t i = ((size_t)blockIdx.x * 256 + threadIdx.x) * 8;
  float4 v0 = *(const float4*)(in + i);
  float4 v1 = *(const float4*)(in + i + 4);
  short8 o;
  o[0] = f2bf(v0.x); o[1] = f2bf(v0.y); o[2] = f2bf(v0.z); o[3] = f2bf(v0.w);
  o[4] = f2bf(v1.x); o[5] = f2bf(v1.y); o[6] = f2bf(v1.z); o[7] = f2bf(v1.w);
  *(short8*)((__hip_bfloat16*)out + i) = o;
}

// ---------------- transpose + cast fp32 (R x C) -> bf16 (C x R) ----------
__global__ __launch_bounds__(256) void transpose_cast_kernel(
    const float* __restrict__ in, __hip_bfloat16* __restrict__ out, int R, int C) {
  __shared__ float tile[32][33];
  int c0 = blockIdx.x * 32, r0 = blockIdx.y * 32;
  int tx = threadIdx.x & 31;
  int ty = threadIdx.x >> 5;  // 0..7
#pragma unroll
  for (int i = 0; i < 4; ++i)
    tile[ty + i * 8][tx] = in[(size_t)(r0 + ty + i * 8) * C + c0 + tx];
  __syncthreads();
#pragma unroll
  for (int i = 0; i < 4; ++i)
    out[(size_t)(c0 + ty + i * 8) * R + r0 + tx] =
        __float2bfloat16(tile[tx][ty + i * 8]);
}

// ---------------- bf16 MFMA GEMM (m97 structure): C = A @ Bt^T + bias ----
// A row-major bf16 [M][Kd], Bt row-major bf16 [N][Kd].
// 128x128 tile, BK=32, 4 waves (2x2), each wave 64x64 = 4x4 frags 16x16x32.
// Staging via global_load_lds width=16, LINEAR LDS (no padding -- required).
static __device__ __forceinline__ void store_out(__hip_bfloat16* p, float v) {
  *p = __float2bfloat16(v);
}
static __device__ __forceinline__ void store_out(float* p, float v) { *p = v; }

template <typename OutT>
__global__ __launch_bounds__(256) void gemm_bt_kernel(
    const __hip_bfloat16* __restrict__ A, const __hip_bfloat16* __restrict__ Bt,
    const float* __restrict__ bias, OutT* __restrict__ C,
    int M, int N, int Kd) {
  // linear [128][32] bf16 tiles (8 KB each)
  __shared__ __align__(16) __hip_bfloat16 As[128 * 32];
  __shared__ __align__(16) __hip_bfloat16 Bs[128 * 32];

  const int t = threadIdx.x;
  const int bn = blockIdx.x, bm = blockIdx.y;
  const int m0 = bm * 128, n0 = bn * 128;
  const int w = t >> 6, lane = t & 63;
  const int wr = w >> 1, wc = w & 1;          // wave -> 64x64 quadrant
  const int lr = lane & 15, kg = lane >> 4;   // frag row, k-group

  // staging granules (8 bf16 = 16 B each); tile = 512 granules.
  // wave w covers g in [w*128, w*128+128), two instructions of 64 lanes.
  const int g0 = w * 128 + lane;
  const int g1 = g0 + 64;
  const int rowA0 = g0 >> 2, kgp0 = g0 & 3;
  const int rowA1 = g1 >> 2, kgp1 = g1 & 3;
  __hip_bfloat16* ldsA0 = As + (size_t)(w * 128) * 8;       // +i*64 granules
  __hip_bfloat16* ldsA1 = As + (size_t)(w * 128 + 64) * 8;
  __hip_bfloat16* ldsB0 = Bs + (size_t)(w * 128) * 8;
  __hip_bfloat16* ldsB1 = Bs + (size_t)(w * 128 + 64) * 8;

  f32x4 acc[4][4] = {};

  const int steps = Kd >> 5;  // BK = 32
  for (int kt = 0; kt < steps; ++kt) {
    const int kcolb = kt * 32;
    gload_lds16(A + (size_t)(m0 + rowA0) * Kd + kcolb + kgp0 * 8, ldsA0);
    gload_lds16(A + (size_t)(m0 + rowA1) * Kd + kcolb + kgp1 * 8, ldsA1);
    gload_lds16(Bt + (size_t)(n0 + rowA0) * Kd + kcolb + kgp0 * 8, ldsB0);
    gload_lds16(Bt + (size_t)(n0 + rowA1) * Kd + kcolb + kgp1 * 8, ldsB1);
    __syncthreads();  // compiler emits vmcnt(0) drain here

    short8 af[4], bfv[4];
#pragma unroll
    for (int mi = 0; mi < 4; ++mi)
      af[mi] = *(const short8*)&As[(wr * 64 + mi * 16 + lr) * 32 + kg * 8];
#pragma unroll
    for (int ni = 0; ni < 4; ++ni)
      bfv[ni] = *(const short8*)&Bs[(wc * 64 + ni * 16 + lr) * 32 + kg * 8];
#pragma unroll
    for (int mi = 0; mi < 4; ++mi)
#pragma unroll
      for (int ni = 0; ni < 4; ++ni)
        acc[mi][ni] = __builtin_amdgcn_mfma_f32_16x16x32_bf16(
            af[mi], bfv[ni], acc[mi][ni], 0, 0, 0);
    __syncthreads();
  }

  // C/D layout (m89-verified): col = lane&15, row = (lane>>4)*4 + reg
#pragma unroll
  for (int mi = 0; mi < 4; ++mi) {
    int row0 = m0 + wr * 64 + mi * 16 + kg * 4;
#pragma unroll
    for (int ni = 0; ni < 4; ++ni) {
      int col = n0 + wc * 64 + ni * 16 + lr;
      float bv = bias[col];
#pragma unroll
      for (int r = 0; r < 4; ++r)
        store_out(&C[(size_t)(row0 + r) * N + col], acc[mi][ni][r] + bv);
    }
  }
}

// ---------------- Spart[c][b,h] = K_h^T @ V_h over 128 L-rows ------------
// grid (128 bh, 8 chunks); partial sums in fp32, summed by qs_kernel.
__global__ __launch_bounds__(256) void ktv_kernel(
    const __hip_bfloat16* __restrict__ qkv, float* __restrict__ Spart) {
  __shared__ __align__(16) float Ks[64][68];
  __shared__ __align__(16) float Vs[64][68];
  const int bh = blockIdx.x;                 // 0..127
  const int ch = blockIdx.y;                 // 0..7
  const int b = bh >> 4, h = bh & 15;
  const __hip_bfloat16* base = qkv + (size_t)b * 1024 * 3072;
  const int hoff = h * 64;
  const int t = threadIdx.x;
  const int i0 = (t >> 4) * 4;   // output row block
  const int j0 = (t & 15) * 4;   // output col block
  const int srow = t >> 2;       // staging row 0..63
  const int sg0 = t & 3;         // staging granule base

  f32x4 acc[4] = {};             // acc[ii] = S[i0+ii][j0..j0+3]

  for (int c = 0; c < 2; ++c) {
    int l0 = ch * 128 + c * 64;
#pragma unroll
    for (int rep = 0; rep < 2; ++rep) {
      int g = sg0 + rep * 4;  // 0..7 granules of 8
      const __hip_bfloat16* rowp = base + (size_t)(l0 + srow) * 3072;
      short8 kv = *(const short8*)(rowp + 1024 + hoff + g * 8);
      short8 vv = *(const short8*)(rowp + 2048 + hoff + g * 8);
      f32x4 k0, k1, v0, v1;
#pragma unroll
      for (int e = 0; e < 4; ++e) {
        k0[e] = bf2f(kv[e]); k1[e] = bf2f(kv[4 + e]);
        v0[e] = bf2f(vv[e]); v1[e] = bf2f(vv[4 + e]);
      }
      *(f32x4*)&Ks[srow][g * 8] = k0;
      *(f32x4*)&Ks[srow][g * 8 + 4] = k1;
      *(f32x4*)&Vs[srow][g * 8] = v0;
      *(f32x4*)&Vs[srow][g * 8 + 4] = v1;
    }
    __syncthreads();
#pragma unroll 8
    for (int l = 0; l < 64; ++l) {
      f32x4 kq = *(const f32x4*)&Ks[l][i0];
      f32x4 vq = *(const f32x4*)&Vs[l][j0];
#pragma unroll
      for (int ii = 0; ii < 4; ++ii) acc[ii] += kq[ii] * vq;
    }
    __syncthreads();
  }

  float* Sp = Spart + ((size_t)ch * 128 + bh) * 4096;
#pragma unroll
  for (int ii = 0; ii < 4; ++ii)
#pragma unroll
    for (int jj = 0; jj < 4; ++jj)
      Sp[(i0 + ii) * 64 + j0 + jj] = acc[ii][jj];
}

// ---------------- attn = Q_h @ S[b,h]  -> bf16 (B*L x D, head-interleaved) -
__global__ __launch_bounds__(256) void qs_kernel(
    const __hip_bfloat16* __restrict__ qkv, const float* __restrict__ Spart,
    __hip_bfloat16* __restrict__ attn) {
  __shared__ __align__(16) float Ql[128][68];
  __shared__ __align__(16) float Sl[64][68];
  const int bh = blockIdx.x;   // 0..127
  const int rblk = blockIdx.y; // 0..7
  const int b = bh >> 4, h = bh & 15;
  const __hip_bfloat16* Qp = qkv + (size_t)b * 1024 * 3072 + h * 64;
  const int r0 = rblk * 128;
  const int t = threadIdx.x;

  // stage Q chunk (128 x 64) as f32
#pragma unroll
  for (int rep = 0; rep < 4; ++rep) {
    int g = t + rep * 256;       // 0..1023 granules of 8
    int row = g >> 3, gg = g & 7;
    short8 qv = *(const short8*)(Qp + (size_t)(r0 + row) * 3072 + gg * 8);
    f32x4 f0, f1;
#pragma unroll
    for (int e = 0; e < 4; ++e) { f0[e] = bf2f(qv[e]); f1[e] = bf2f(qv[4 + e]); }
    *(f32x4*)&Ql[row][gg * 8] = f0;
    *(f32x4*)&Ql[row][gg * 8 + 4] = f1;
  }
  // stage S (64 x 64 f32): sum the 8 chunk-partials, apply 1/8 scale
#pragma unroll
  for (int rep = 0; rep < 4; ++rep) {
    int g = t + rep * 256;        // 0..1023 float4 granules
    int row = g >> 4, gg = g & 15;
    f32x4 s = {};
#pragma unroll
    for (int c = 0; c < 8; ++c)
      s += *(const f32x4*)&Spart[((size_t)c * 128 + bh) * 4096 + row * 64 + gg * 4];
    *(f32x4*)&Sl[row][gg * 4] = s * 0.125f;
  }
  __syncthreads();

  const int rt0 = (t >> 3) * 4;   // 4 rows
  const int j0 = (t & 7) * 8;     // 8 cols
  f32x4 accA[4] = {}, accB[4] = {};
#pragma unroll 4
  for (int i = 0; i < 64; i += 4) {
    f32x4 q[4], s0[4], s1[4];
#pragma unroll
    for (int rr = 0; rr < 4; ++rr) q[rr] = *(const f32x4*)&Ql[rt0 + rr][i];
#pragma unroll
    for (int ii = 0; ii < 4; ++ii) {
      s0[ii] = *(const f32x4*)&Sl[i + ii][j0];
      s1[ii] = *(const f32x4*)&Sl[i + ii][j0 + 4];
    }
#pragma unroll
    for (int ii = 0; ii < 4; ++ii)
#pragma unroll
      for (int rr = 0; rr < 4; ++rr) {
        accA[rr] += q[rr][ii] * s0[ii];
        accB[rr] += q[rr][ii] * s1[ii];
      }
  }

#pragma unroll
  for (int rr = 0; rr < 4; ++rr) {
    short8 o;
#pragma unroll
    for (int e = 0; e < 4; ++e) {
      o[e] = f2bf(accA[rr][e]);
      o[4 + e] = f2bf(accB[rr][e]);
    }
    *(short8*)(attn + (size_t)(b * 1024 + r0 + rt0 + rr) * 1024 + h * 64 + j0) = o;
  }
}

extern "C" void kernel_launch(void* const* d_in, const int* in_sizes, int n_in,
                              void* d_out, int out_size, void* d_ws, size_t ws_size,
                              hipStream_t stream) {
  const float* x = (const float*)d_in[0];
  const float* w_in = (const float*)d_in[1];
  const float* b_in = (const float*)d_in[2];
  const float* w_out = (const float*)d_in[3];
  const float* b_out = (const float*)d_in[4];
  float* out = (float*)d_out;

  char* ws = (char*)d_ws;
  __hip_bfloat16* x_bf = (__hip_bfloat16*)ws;   ws += (size_t)8192 * 1024 * 2;
  __hip_bfloat16* w_inT = (__hip_bfloat16*)ws;  ws += (size_t)3072 * 1024 * 2;
  __hip_bfloat16* w_outT = (__hip_bfloat16*)ws; ws += (size_t)1024 * 1024 * 2;
  __hip_bfloat16* qkv = (__hip_bfloat16*)ws;    ws += (size_t)8192 * 3072 * 2;
  float* Spart = (float*)ws;                    ws += (size_t)8 * 128 * 64 * 64 * 4;
  __hip_bfloat16* attn = (__hip_bfloat16*)ws;   ws += (size_t)8192 * 1024 * 2;

  // casts / transposes
  cast_f32_bf16_kernel<<<4096, 256, 0, stream>>>(x, x_bf);              // 8192x1024
  transpose_cast_kernel<<<dim3(96, 32), 256, 0, stream>>>(w_in, w_inT, 1024, 3072);
  transpose_cast_kernel<<<dim3(32, 32), 256, 0, stream>>>(w_out, w_outT, 1024, 1024);

  // GEMM1: qkv = x @ w_in + b_in   (8192 x 3072, Kd=1024) -> bf16
  gemm_bt_kernel<__hip_bfloat16><<<dim3(24, 64), 256, 0, stream>>>(
      x_bf, w_inT, b_in, qkv, 8192, 3072, 1024);

  // S partials = Kt V per (b,h) over 128-row chunks
  ktv_kernel<<<dim3(128, 8), 256, 0, stream>>>(qkv, Spart);

  // attn = Q @ S per (b,h)
  qs_kernel<<<dim3(128, 8), 256, 0, stream>>>(qkv, Spart, attn);

  // GEMM4: out = attn @ w_out + b_out  (8192 x 1024, Kd=1024) -> fp32
  gemm_bt_kernel<float><<<dim3(8, 64), 256, 0, stream>>>(
      attn, w_outT, b_out, out, 8192, 1024, 1024);
}